// Round 4
// baseline (353.373 us; speedup 1.0000x reference)
//
#include <hip/hip_runtime.h>
#include <math.h>

#define SEQ 65536
#define FEAT 512
#define NCH 256
#define CHUNK 256
#define THRES1 0.8f
#define THRES_UP 0.5f
#define NEGINF -1e30f

#define AL(p)     __hip_atomic_load((p), __ATOMIC_RELAXED, __HIP_MEMORY_SCOPE_AGENT)
#define AS(p, v)  __hip_atomic_store((p), (v), __ATOMIC_RELEASE, __HIP_MEMORY_SCOPE_AGENT)

// ---------------- K1: a = sigmoid(h @ W + b), one wave per row ----------------
// Block 0 also zeroes the 4 x 256 publish-flag arrays for the scan kernel.
__global__ __launch_bounds__(256) void k_matvec(const float* __restrict__ h,
                                                const float* __restrict__ W,
                                                const float* __restrict__ b,
                                                float* __restrict__ a,
                                                unsigned* __restrict__ flags) {
    if (blockIdx.x == 0) {
        #pragma unroll
        for (int k = 0; k < 4; ++k) flags[k * 256 + threadIdx.x] = 0u;
    }
    int wave = threadIdx.x >> 6;
    int lane = threadIdx.x & 63;
    int row  = blockIdx.x * 4 + wave;
    const float4* hp = (const float4*)(h + (size_t)row * FEAT);
    const float4* wp = (const float4*)W;
    int base = lane * 2;  // each lane: elements [lane*8, lane*8+8)
    float4 h0 = hp[base], h1 = hp[base + 1];
    float4 w0 = wp[base], w1 = wp[base + 1];
    float s = h0.x * w0.x + h0.y * w0.y + h0.z * w0.z + h0.w * w0.w
            + h1.x * w1.x + h1.y * w1.y + h1.z * w1.z + h1.w * w1.w;
    #pragma unroll
    for (int off = 32; off; off >>= 1) s += __shfl_down(s, off, 64);
    if (lane == 0) a[row] = 1.0f / (1.0f + expf(-(s + b[0])));
}

// Wait until flags[0..upto-1] are all set. Lane t polls flag t; backward-only
// dependencies make this deadlock-free (block c never waits on blocks >= c).
__device__ __forceinline__ void wait_flags(unsigned* flags, int upto, int t) {
    bool ok;
    do {
        unsigned f = (t < upto) ? AL(flags + t) : 1u;
        ok = __syncthreads_and((int)(f != 0u)) != 0;
        if (!ok) __builtin_amdgcn_s_sleep(1);
    } while (!ok);
    __threadfence();  // acquire: make published data visible across XCDs
}

// All threads' prior writes -> visible, then set flag c.
__device__ __forceinline__ void publish(unsigned* flags, int c, int t) {
    __syncthreads();
    if (t == 0) {
        __threadfence();  // release
        AS(flags + c, 1u);
    }
}

__device__ __forceinline__ void affine_scan256(float* sc, float* sd, int t) {
    // callers must __syncthreads() after writing init values, before calling
    for (int d = 1; d < 256; d <<= 1) {
        float lc = 1.0f, ld = 0.0f;
        bool act = t >= d;
        if (act) { lc = sc[t - d]; ld = sd[t - d]; }
        __syncthreads();
        if (act) { sd[t] = sc[t] * ld + sd[t]; sc[t] = sc[t] * lc; }
        __syncthreads();
    }
}

// -------- K2 (cooperative): entire scan pipeline, chained-flag sync --------
__global__ __launch_bounds__(256) void k_scan(const float* __restrict__ u_pred,
                                              const float* __restrict__ label,
                                              const float* __restrict__ thres2,
                                              const float* __restrict__ a,
                                              float* __restrict__ out,
                                              float* __restrict__ sf_,
                                              int* __restrict__ si_,
                                              unsigned* __restrict__ flags) {
    __shared__ float sA[256], sB[256], sU[256];
    __shared__ int   iA[256], iB[256], iC[256];

    int t = threadIdx.x, c = blockIdx.x;
    int i = c * CHUNK + t;

    float* lastm = sf_;
    float* Pch   = sf_ + NCH;
    float* Qch   = sf_ + 2 * NCH;
    float* Ech   = sf_ + 3 * NCH;
    float* Fch   = sf_ + 4 * NCH;
    int* lastopen = si_;
    int* lastgate = si_ + NCH;
    int* trigLast = si_ + 2 * NCH;
    int* fallLast = si_ + 3 * NCH;
    unsigned* flags1 = flags;
    unsigned* flags2 = flags + NCH;
    unsigned* flags3 = flags + 2 * NCH;
    unsigned* flags4 = flags + 3 * NCH;

    // ---------- Phase 1: local scans over chunk c ----------
    float u   = u_pred[i];
    float lab = label[i];
    float a_i = a[i];
    sU[t] = u;
    __syncthreads();
    bool gate = u >= THRES_UP;
    bool gprevLocal = (t > 0) && (sU[t - 1] >= THRES_UP);
    bool gprev = (t > 0) ? gprevLocal : ((i > 0) && (u_pred[i - 1] >= THRES_UP));
    bool fall = gprev && !gate;
    bool trig = lab >= THRES1;

    sA[t] = gate ? u : NEGINF;                               // segmented run-max
    iA[t] = gate ? ((t > 0 && !gprevLocal) ? 1 : 0) : 1;     // boundary flag
    iB[t] = trig ? i : -1;                                   // last trigger idx
    iC[t] = fall ? i : -1;                                   // last fall idx
    __syncthreads();
    for (int d = 1; d < 256; d <<= 1) {
        float lm = NEGINF; int lr = 0, lt_ = -1, lf_ = -1;
        bool act = t >= d;
        if (act) { lm = sA[t - d]; lr = iA[t - d]; lt_ = iB[t - d]; lf_ = iC[t - d]; }
        __syncthreads();
        if (act) {
            if (!iA[t]) sA[t] = fmaxf(lm, sA[t]);
            iA[t] |= lr;
            iB[t] = max(iB[t], lt_);
            iC[t] = max(iC[t], lf_);
        }
        __syncthreads();
    }
    float m_loc = sA[t];
    int   open  = (iA[t] == 0 && gate) ? 1 : 0;
    int   lt    = iB[t];
    int   lfE   = (t == 0) ? -1 : iC[t - 1];
    if (t == 255) {
        lastm[c]    = sA[255];
        lastopen[c] = open;
        lastgate[c] = gate ? 1 : 0;
        trigLast[c] = iB[255];
        fallLast[c] = iC[255];
    }
    if (c == 0 && t == 0) { out[4 * SEQ] = 0.0f; out[4 * SEQ + 1] = 0.0f; }
    publish(flags1, c, t);

    // ---------- Phase 2: prefix over chunk summaries (need only 0..c-1) ----------
    wait_flags(flags1, c, t);
    {
        float lm_ = AL(lastm + t);
        int   lo_ = AL(lastopen + t);
        int   lg_ = AL(lastgate + t);
        iA[t] = AL(trigLast + t);
        iB[t] = AL(fallLast + t);
        bool lg = lg_ != 0;
        sA[t] = lg ? lm_ : NEGINF;
        sB[t] = (lg && lo_) ? 0.0f : NEGINF;
    }
    __syncthreads();
    for (int d = 1; d < 256; d <<= 1) {
        float lA = NEGINF, lB = NEGINF; int lt_ = -1, lf_ = -1;
        bool act = t >= d;
        if (act) { lA = sA[t - d]; lB = sB[t - d]; lt_ = iA[t - d]; lf_ = iB[t - d]; }
        __syncthreads();
        if (act) {
            float nA = fmaxf(sA[t], sB[t] + lA);   // max-plus compose right∘left
            float nB = fmaxf(sB[t] + lB, NEGINF);
            sA[t] = nA; sB[t] = nB;
            iA[t] = max(iA[t], lt_);
            iB[t] = max(iB[t], lf_);
        }
        __syncthreads();
    }
    float inc_c; int trigIn_c, fallIn_c;
    if (c == 0) { inc_c = NEGINF; trigIn_c = -1; fallIn_c = -1; }
    else        { inc_c = sA[c - 1]; trigIn_c = iA[c - 1]; fallIn_c = iB[c - 1]; }
    __syncthreads();

    // ---------- Phase 3: finalize up_hat, local alpha affine scan ----------
    float uh = gate ? (open ? fmaxf(m_loc, inc_c) : m_loc) : u;
    out[3 * SEQ + i] = uh;   // up_hats
    out[2 * SEQ + i] = u;    // u_pred passthrough
    sA[t] = uh;
    sB[t] = (1.0f - uh) * a_i;
    __syncthreads();
    affine_scan256(sA, sB, t);
    float Pt = sA[t], Qt = sB[t];
    if (t == 255) { Pch[c] = Pt; Qch[c] = Qt; }
    publish(flags2, c, t);

    // ---------- Phase 4: alpha incoming, finalize alpha, local y affine scan ----------
    wait_flags(flags2, c, t);
    sA[t] = AL(Pch + t); sB[t] = AL(Qch + t);
    __syncthreads();
    affine_scan256(sA, sB, t);
    float alphaIn_c = (c == 0) ? 0.0f : sB[c - 1];
    __syncthreads();
    float al = Pt * alphaIn_c + Qt;
    out[SEQ + i] = al;  // alphas
    sA[t] = gate ? (1.0f - al) : 0.0f;
    sB[t] = gate ? al * uh : 0.0f;
    __syncthreads();
    affine_scan256(sA, sB, t);
    float Et = sA[t], Ft = sB[t];
    if (t == 255) { Ech[c] = Et; Fch[c] = Ft; }
    publish(flags3, c, t);

    // ---------- Phase 5: y incoming, finalize y ----------
    wait_flags(flags3, c, t);
    sA[t] = AL(Ech + t); sB[t] = AL(Fch + t);
    __syncthreads();
    affine_scan256(sA, sB, t);
    float yIn_c = (c == 0) ? 0.0f : sB[c - 1];
    float y_i = Et * yIn_c + Ft;
    out[i] = y_i;  // ys
    publish(flags4, c, t);

    // ---------- Phase 6: loss/cnt at gate falling edges (needs y of chunks <= c) ----------
    wait_flags(flags4, c + 1, t);
    float contrib = 0.0f;
    int flag = 0;
    if (fall) {
        int j  = max(lt, trigIn_c);    // last label-trigger <= i
        int pf = max(lfE, fallIn_c);   // last fall < i
        float lc = 0.0f;
        if (j > pf) {
            bool gj = u_pred[j] >= THRES_UP;
            float d = AL(out + j) - label[j];
            lc = gj ? d * d : -1.0f;
        }
        bool isneg = (lc == -1.0f);
        bool nonzero = (lc != 0.0f);
        if (!isneg) {
            if (nonzero) { contrib = lc; flag = 1; }   // * R, R = 1.0
            else {
                float ypre = AL(out + (i - 1));
                if (ypre >= THRES1) {
                    float t2 = thres2[(i < 59) ? i : 59];
                    float d2 = ypre - t2;
                    contrib = d2 * d2; flag = 1;
                }
            }
        }
    }
    #pragma unroll
    for (int off = 32; off; off >>= 1) {
        contrib += __shfl_down(contrib, off, 64);
        flag    += __shfl_down(flag, off, 64);
    }
    if ((t & 63) == 0 && (contrib != 0.0f || flag != 0)) {
        atomicAdd(&out[4 * SEQ], contrib);
        atomicAdd(&out[4 * SEQ + 1], (float)flag);
    }
}

extern "C" void kernel_launch(void* const* d_in, const int* in_sizes, int n_in,
                              void* d_out, int out_size, void* d_ws, size_t ws_size,
                              hipStream_t stream) {
    const float* h      = (const float*)d_in[0];
    const float* W      = (const float*)d_in[1];
    const float* b      = (const float*)d_in[2];
    const float* u_pred = (const float*)d_in[4];
    const float* label  = (const float*)d_in[5];
    const float* thres2 = (const float*)d_in[6];
    float* out  = (float*)d_out;
    float* base = (float*)d_ws;

    float* a   = base;                            // SEQ floats
    float* sf_ = base + SEQ;                      // 5*NCH floats
    int*   si_ = (int*)(base + SEQ + 5 * NCH);    // 4*NCH ints
    unsigned* flags = (unsigned*)(si_ + 4 * NCH); // 4*NCH flags

    k_matvec<<<SEQ / 4, 256, 0, stream>>>(h, W, b, a, flags);

    void* args[] = { (void*)&u_pred, (void*)&label, (void*)&thres2, (void*)&a,
                     (void*)&out, (void*)&sf_, (void*)&si_, (void*)&flags };
    hipLaunchCooperativeKernel((void*)k_scan, dim3(NCH), dim3(256), args, 0, stream);
}

// Round 6
// 240.902 us; speedup vs baseline: 1.4669x; 1.4669x over previous
//
#include <hip/hip_runtime.h>
#include <math.h>

#define SEQ 65536
#define FEAT 512
#define NCH 256
#define CHUNK 256
#define THRES1 0.8f
#define THRES_UP 0.5f
#define NEGINF -1e30f

// ---- L1: a = sigmoid(h @ W + b) (one wave per row); blocks 0..255 also do
//          the per-chunk local scans (independent inputs, hidden under matvec).
__global__ __launch_bounds__(256) void k_matvec_local(
        const float* __restrict__ h, const float* __restrict__ W,
        const float* __restrict__ b, const float* __restrict__ u_pred,
        const float* __restrict__ label,
        float* __restrict__ a,
        float* __restrict__ m_loc, int* __restrict__ openA,
        int* __restrict__ ltLoc, int* __restrict__ lfExcl,
        float* __restrict__ lastm, int* __restrict__ lastopen,
        int* __restrict__ lastgate, int* __restrict__ trigLast,
        int* __restrict__ fallLast) {
    // ---- matvec part (all blocks) ----
    {
        int wave = threadIdx.x >> 6;
        int lane = threadIdx.x & 63;
        int row  = blockIdx.x * 4 + wave;
        const float4* hp = (const float4*)(h + (size_t)row * FEAT);
        const float4* wp = (const float4*)W;
        int base = lane * 2;  // each lane: elements [lane*8, lane*8+8)
        float4 h0 = hp[base], h1 = hp[base + 1];
        float4 w0 = wp[base], w1 = wp[base + 1];
        float s = h0.x * w0.x + h0.y * w0.y + h0.z * w0.z + h0.w * w0.w
                + h1.x * w1.x + h1.y * w1.y + h1.z * w1.z + h1.w * w1.w;
        #pragma unroll
        for (int off = 32; off; off >>= 1) s += __shfl_down(s, off, 64);
        if (lane == 0) a[row] = 1.0f / (1.0f + expf(-(s + b[0])));
    }
    // ---- local scans (blocks 0..255 only; block-uniform branch) ----
    if (blockIdx.x < NCH) {
        __shared__ float su[256];
        __shared__ float sm[256];
        __shared__ int   sr[256];
        __shared__ int   st[256];
        __shared__ int   sf[256];
        int t = threadIdx.x, c = blockIdx.x;
        int i = c * CHUNK + t;
        float u = u_pred[i];
        su[t] = u;
        __syncthreads();
        bool gate = u >= THRES_UP;
        bool gprevLocal = (t > 0) && (su[t - 1] >= THRES_UP);
        bool gprev = (t > 0) ? gprevLocal : ((i > 0) && (u_pred[i - 1] >= THRES_UP));
        bool fall = gprev && !gate;
        bool trig = label[i] >= THRES1;

        sm[t] = gate ? u : NEGINF;                               // segmented run-max
        sr[t] = gate ? ((t > 0 && !gprevLocal) ? 1 : 0) : 1;     // boundary flag
        st[t] = trig ? i : -1;                                   // last trigger idx
        sf[t] = fall ? i : -1;                                   // last fall idx
        __syncthreads();
        for (int d = 1; d < 256; d <<= 1) {
            float lm = NEGINF; int lr = 0, lt = -1, lf = -1;
            bool act = t >= d;
            if (act) { lm = sm[t - d]; lr = sr[t - d]; lt = st[t - d]; lf = sf[t - d]; }
            __syncthreads();
            if (act) {
                if (!sr[t]) sm[t] = fmaxf(lm, sm[t]);
                sr[t] |= lr;
                st[t] = max(st[t], lt);
                sf[t] = max(sf[t], lf);
            }
            __syncthreads();
        }
        m_loc[i]  = sm[t];
        openA[i]  = (sr[t] == 0 && gate) ? 1 : 0;
        ltLoc[i]  = st[t];
        lfExcl[i] = (t == 0) ? -1 : sf[t - 1];
        if (t == 255) {
            lastm[c]    = sm[255];
            lastopen[c] = (sr[255] == 0 && gate) ? 1 : 0;
            lastgate[c] = gate ? 1 : 0;
            trigLast[c] = st[255];
            fallLast[c] = sf[255];
        }
    }
}

// ---- L2: cross-chunk summary scan (1 block): inc, trigIn, fallIn; zero loss ----
__global__ __launch_bounds__(256) void k_mid1(const float* __restrict__ lastm,
                                              const int* __restrict__ lastopen,
                                              const int* __restrict__ lastgate,
                                              const int* __restrict__ trigLast,
                                              const int* __restrict__ fallLast,
                                              float* __restrict__ inc, int* __restrict__ trigIn,
                                              int* __restrict__ fallIn,
                                              float* __restrict__ losscnt) {
    __shared__ float sA[256], sB[256];
    __shared__ int   st[256], sf[256];
    int t = threadIdx.x;
    bool lg = lastgate[t] != 0;
    sA[t] = lg ? lastm[t] : NEGINF;
    sB[t] = (lg && lastopen[t]) ? 0.0f : NEGINF;
    st[t] = trigLast[t];
    sf[t] = fallLast[t];
    __syncthreads();
    for (int d = 1; d < 256; d <<= 1) {
        float lA = NEGINF, lB = NEGINF; int lt = -1, lf = -1;
        bool act = t >= d;
        if (act) { lA = sA[t - d]; lB = sB[t - d]; lt = st[t - d]; lf = sf[t - d]; }
        __syncthreads();
        if (act) {
            float nA = fmaxf(sA[t], sB[t] + lA);   // max-plus compose right∘left
            float nB = fmaxf(sB[t] + lB, NEGINF);
            sA[t] = nA; sB[t] = nB;
            st[t] = max(st[t], lt);
            sf[t] = max(sf[t], lf);
        }
        __syncthreads();
    }
    inc[t]    = (t == 0) ? NEGINF : sA[t - 1];
    trigIn[t] = (t == 0) ? -1 : st[t - 1];
    fallIn[t] = (t == 0) ? -1 : sf[t - 1];
    if (t == 0) { losscnt[0] = 0.0f; losscnt[1] = 0.0f; }
}

// ---- L3: finalize up_hat; per-chunk affine scan of alpha pairs ----
__global__ __launch_bounds__(256) void k_uphat_alpha(const float* __restrict__ u_pred,
                                                     const float* __restrict__ a,
                                                     const float* __restrict__ m_loc,
                                                     const int* __restrict__ openA,
                                                     const float* __restrict__ inc,
                                                     float* __restrict__ Pc, float* __restrict__ Qc,
                                                     float* __restrict__ Pch, float* __restrict__ Qch,
                                                     float* __restrict__ out) {
    __shared__ float sc[256], sd[256];
    int t = threadIdx.x, c = blockIdx.x;
    int i = c * CHUNK + t;
    float u = u_pred[i];
    bool gate = u >= THRES_UP;
    float uh = gate ? (openA[i] ? fmaxf(m_loc[i], inc[c]) : m_loc[i]) : u;
    out[3 * SEQ + i] = uh;   // up_hats
    out[2 * SEQ + i] = u;    // u_pred passthrough
    sc[t] = uh;
    sd[t] = (1.0f - uh) * a[i];
    __syncthreads();
    for (int d = 1; d < 256; d <<= 1) {
        float lc = 1.0f, ld = 0.0f;
        bool act = t >= d;
        if (act) { lc = sc[t - d]; ld = sd[t - d]; }
        __syncthreads();
        if (act) { sd[t] = sc[t] * ld + sd[t]; sc[t] = sc[t] * lc; }
        __syncthreads();
    }
    Pc[i] = sc[t];
    Qc[i] = sd[t];
    if (t == 255) { Pch[c] = sc[255]; Qch[c] = sd[255]; }
}

// ---- tiny affine scan over 256 chunk summaries (alphaIn / yIn) ----
__global__ __launch_bounds__(256) void k_mid_affine(const float* __restrict__ P,
                                                    const float* __restrict__ Q,
                                                    float* __restrict__ res) {
    __shared__ float sc[256], sd[256];
    int t = threadIdx.x;
    sc[t] = P[t]; sd[t] = Q[t];
    __syncthreads();
    for (int d = 1; d < 256; d <<= 1) {
        float lc = 1.0f, ld = 0.0f;
        bool act = t >= d;
        if (act) { lc = sc[t - d]; ld = sd[t - d]; }
        __syncthreads();
        if (act) { sd[t] = sc[t] * ld + sd[t]; sc[t] = sc[t] * lc; }
        __syncthreads();
    }
    res[t] = (t == 0) ? 0.0f : sd[t - 1];
}

// ---- L5: finalize alpha; per-chunk affine scan of y pairs (into Pc/Qc) ----
__global__ __launch_bounds__(256) void k_alpha_y(float* __restrict__ Pc, float* __restrict__ Qc,
                                                 const float* __restrict__ alphaIn,
                                                 float* __restrict__ out,
                                                 float* __restrict__ Ech, float* __restrict__ Fch) {
    __shared__ float sc[256], sd[256];
    int t = threadIdx.x, c = blockIdx.x;
    int i = c * CHUNK + t;
    float al = Pc[i] * alphaIn[c] + Qc[i];
    out[SEQ + i] = al;  // alphas
    float uh = out[3 * SEQ + i];
    bool gate = uh >= THRES_UP;
    sc[t] = gate ? (1.0f - al) : 0.0f;
    sd[t] = gate ? al * uh : 0.0f;
    __syncthreads();
    for (int d = 1; d < 256; d <<= 1) {
        float lc = 1.0f, ld = 0.0f;
        bool act = t >= d;
        if (act) { lc = sc[t - d]; ld = sd[t - d]; }
        __syncthreads();
        if (act) { sd[t] = sc[t] * ld + sd[t]; sc[t] = sc[t] * lc; }
        __syncthreads();
    }
    Pc[i] = sc[t];  // Ec
    Qc[i] = sd[t];  // Fc
    if (t == 255) { Ech[c] = sc[255]; Fch[c] = sd[255]; }
}

// ---- L7: finalize y AND loss/cnt (y[j] recomputed from Ec/Fc/yIn — no
//          dependence on out[] written by other blocks in this launch) ----
__global__ __launch_bounds__(256) void k_yfinal_loss(const float* __restrict__ Ec,
                                                     const float* __restrict__ Fc,
                                                     const float* __restrict__ yIn,
                                                     const float* __restrict__ u_pred,
                                                     const float* __restrict__ label,
                                                     const float* __restrict__ thres2,
                                                     const int* __restrict__ ltLoc,
                                                     const int* __restrict__ lfExcl,
                                                     const int* __restrict__ trigIn,
                                                     const int* __restrict__ fallIn,
                                                     float* __restrict__ out) {
    int t = threadIdx.x, c = blockIdx.x;
    int i = c * CHUNK + t;
    out[i] = Ec[i] * yIn[c] + Fc[i];  // ys

    float u = u_pred[i];
    bool gate = u >= THRES_UP;
    bool gprev = (i > 0) && (u_pred[i - 1] >= THRES_UP);
    bool fall = gprev && !gate;
    float contrib = 0.0f;
    int flag = 0;
    if (fall) {
        int j  = max(ltLoc[i], trigIn[c]);    // last label-trigger <= i
        int pf = max(lfExcl[i], fallIn[c]);   // last fall < i
        float lc = 0.0f;
        if (j > pf) {
            bool gj = u_pred[j] >= THRES_UP;
            float yj = Ec[j] * yIn[j >> 8] + Fc[j];
            float d = yj - label[j];
            lc = gj ? d * d : -1.0f;
        }
        bool isneg = (lc == -1.0f);
        bool nonzero = (lc != 0.0f);
        if (!isneg) {
            if (nonzero) { contrib = lc; flag = 1; }   // * R, R = 1.0
            else {
                int ip = i - 1;
                float ypre = Ec[ip] * yIn[ip >> 8] + Fc[ip];
                if (ypre >= THRES1) {
                    float t2 = thres2[(i < 59) ? i : 59];
                    float d2 = ypre - t2;
                    contrib = d2 * d2; flag = 1;
                }
            }
        }
    }
    #pragma unroll
    for (int off = 32; off; off >>= 1) {
        contrib += __shfl_down(contrib, off, 64);
        flag    += __shfl_down(flag, off, 64);
    }
    if ((t & 63) == 0 && (contrib != 0.0f || flag != 0)) {
        atomicAdd(&out[4 * SEQ], contrib);
        atomicAdd(&out[4 * SEQ + 1], (float)flag);
    }
}

extern "C" void kernel_launch(void* const* d_in, const int* in_sizes, int n_in,
                              void* d_out, int out_size, void* d_ws, size_t ws_size,
                              hipStream_t stream) {
    const float* h      = (const float*)d_in[0];
    const float* W      = (const float*)d_in[1];
    const float* b      = (const float*)d_in[2];
    const float* u_pred = (const float*)d_in[4];
    const float* label  = (const float*)d_in[5];
    const float* thres2 = (const float*)d_in[6];
    float* out  = (float*)d_out;
    float* base = (float*)d_ws;

    float* a      = base;
    float* m_loc  = base + SEQ;
    float* Pc     = base + 2 * (size_t)SEQ;
    float* Qc     = base + 3 * (size_t)SEQ;
    int*   openA  = (int*)(base + 4 * (size_t)SEQ);
    int*   ltLoc  = (int*)(base + 5 * (size_t)SEQ);
    int*   lfExcl = (int*)(base + 6 * (size_t)SEQ);
    float* sums   = base + 7 * (size_t)SEQ;
    float* lastm   = sums;
    float* Pch     = sums + NCH;
    float* Qch     = sums + 2 * NCH;
    float* inc     = sums + 3 * NCH;
    float* alphaIn = sums + 4 * NCH;
    float* yIn     = sums + 5 * NCH;
    int*   lastopen = (int*)(sums + 6 * NCH);
    int*   lastgate = (int*)(sums + 7 * NCH);
    int*   trigLast = (int*)(sums + 8 * NCH);
    int*   fallLast = (int*)(sums + 9 * NCH);
    int*   trigIn   = (int*)(sums + 10 * NCH);
    int*   fallIn   = (int*)(sums + 11 * NCH);

    k_matvec_local<<<SEQ / 4, 256, 0, stream>>>(h, W, b, u_pred, label, a,
                                                m_loc, openA, ltLoc, lfExcl,
                                                lastm, lastopen, lastgate, trigLast, fallLast);
    k_mid1<<<1, NCH, 0, stream>>>(lastm, lastopen, lastgate, trigLast, fallLast,
                                  inc, trigIn, fallIn, out + 4 * SEQ);
    k_uphat_alpha<<<NCH, CHUNK, 0, stream>>>(u_pred, a, m_loc, openA, inc, Pc, Qc, Pch, Qch, out);
    k_mid_affine<<<1, NCH, 0, stream>>>(Pch, Qch, alphaIn);
    k_alpha_y<<<NCH, CHUNK, 0, stream>>>(Pc, Qc, alphaIn, out, Pch, Qch);
    k_mid_affine<<<1, NCH, 0, stream>>>(Pch, Qch, yIn);
    k_yfinal_loss<<<NCH, CHUNK, 0, stream>>>(Pc, Qc, yIn, u_pred, label, thres2,
                                             ltLoc, lfExcl, trigIn, fallIn, out);
}

// Round 7
// 235.456 us; speedup vs baseline: 1.5008x; 1.0231x over previous
//
#include <hip/hip_runtime.h>
#include <math.h>

#define SEQ 65536
#define FEAT 512
#define NCH 256
#define CHUNK 256
#define THRES1 0.8f
#define THRES_UP 0.5f
#define NEGINF -1e30f

// ---- L1: a = sigmoid(h @ W + b) (one wave per row); blocks 0..255 also do
//          the per-chunk local scans; block 0 zeroes loss/cnt.
__global__ __launch_bounds__(256) void k_matvec_local(
        const float* __restrict__ h, const float* __restrict__ W,
        const float* __restrict__ b, const float* __restrict__ u_pred,
        const float* __restrict__ label,
        float* __restrict__ a,
        float* __restrict__ m_loc, int* __restrict__ openA,
        int* __restrict__ ltLoc, int* __restrict__ lfExcl,
        float* __restrict__ lastm, int* __restrict__ lastopen,
        int* __restrict__ lastgate, int* __restrict__ trigLast,
        int* __restrict__ fallLast, float* __restrict__ losscnt) {
    // ---- matvec part (all blocks) ----
    {
        int wave = threadIdx.x >> 6;
        int lane = threadIdx.x & 63;
        int row  = blockIdx.x * 4 + wave;
        const float4* hp = (const float4*)(h + (size_t)row * FEAT);
        const float4* wp = (const float4*)W;
        int base = lane * 2;  // each lane: elements [lane*8, lane*8+8)
        float4 h0 = hp[base], h1 = hp[base + 1];
        float4 w0 = wp[base], w1 = wp[base + 1];
        float s = h0.x * w0.x + h0.y * w0.y + h0.z * w0.z + h0.w * w0.w
                + h1.x * w1.x + h1.y * w1.y + h1.z * w1.z + h1.w * w1.w;
        #pragma unroll
        for (int off = 32; off; off >>= 1) s += __shfl_down(s, off, 64);
        if (lane == 0) a[row] = 1.0f / (1.0f + expf(-(s + b[0])));
    }
    if (blockIdx.x == 0 && threadIdx.x == 0) { losscnt[0] = 0.0f; losscnt[1] = 0.0f; }
    // ---- local scans (blocks 0..255 only; block-uniform branch) ----
    if (blockIdx.x < NCH) {
        __shared__ float su[256];
        __shared__ float sm[256];
        __shared__ int   sr[256];
        __shared__ int   st[256];
        __shared__ int   sf[256];
        int t = threadIdx.x, c = blockIdx.x;
        int i = c * CHUNK + t;
        float u = u_pred[i];
        su[t] = u;
        __syncthreads();
        bool gate = u >= THRES_UP;
        bool gprevLocal = (t > 0) && (su[t - 1] >= THRES_UP);
        bool gprev = (t > 0) ? gprevLocal : ((i > 0) && (u_pred[i - 1] >= THRES_UP));
        bool fall = gprev && !gate;
        bool trig = label[i] >= THRES1;

        sm[t] = gate ? u : NEGINF;                               // segmented run-max
        sr[t] = gate ? ((t > 0 && !gprevLocal) ? 1 : 0) : 1;     // boundary flag
        st[t] = trig ? i : -1;                                   // last trigger idx
        sf[t] = fall ? i : -1;                                   // last fall idx
        __syncthreads();
        for (int d = 1; d < 256; d <<= 1) {
            float lm = NEGINF; int lr = 0, lt = -1, lf = -1;
            bool act = t >= d;
            if (act) { lm = sm[t - d]; lr = sr[t - d]; lt = st[t - d]; lf = sf[t - d]; }
            __syncthreads();
            if (act) {
                if (!sr[t]) sm[t] = fmaxf(lm, sm[t]);
                sr[t] |= lr;
                st[t] = max(st[t], lt);
                sf[t] = max(sf[t], lf);
            }
            __syncthreads();
        }
        m_loc[i]  = sm[t];
        openA[i]  = (sr[t] == 0 && gate) ? 1 : 0;
        ltLoc[i]  = st[t];
        lfExcl[i] = (t == 0) ? -1 : sf[t - 1];
        if (t == 255) {
            lastm[c]    = sm[255];
            lastopen[c] = (sr[255] == 0 && gate) ? 1 : 0;
            lastgate[c] = gate ? 1 : 0;
            trigLast[c] = st[255];
            fallLast[c] = sf[255];
        }
    }
}

// ---- L2: redundant cross-chunk max-plus scan -> inc_c; finalize up_hat;
//          per-chunk affine scan of alpha pairs ----
__global__ __launch_bounds__(256) void k_uphat_alpha(
        const float* __restrict__ u_pred, const float* __restrict__ a,
        const float* __restrict__ m_loc, const int* __restrict__ openA,
        const float* __restrict__ lastm, const int* __restrict__ lastopen,
        const int* __restrict__ lastgate,
        float* __restrict__ Pc, float* __restrict__ Qc,
        float* __restrict__ Pch, float* __restrict__ Qch,
        float* __restrict__ out) {
    __shared__ float sc[256], sd[256];
    int t = threadIdx.x, c = blockIdx.x;
    int i = c * CHUNK + t;

    // redundant max-plus scan over chunk summaries (each block computes all)
    {
        bool lg = lastgate[t] != 0;
        sc[t] = lg ? lastm[t] : NEGINF;                 // A
        sd[t] = (lg && lastopen[t]) ? 0.0f : NEGINF;    // B
    }
    __syncthreads();
    for (int d = 1; d < 256; d <<= 1) {
        float lA = NEGINF, lB = NEGINF;
        bool act = t >= d;
        if (act) { lA = sc[t - d]; lB = sd[t - d]; }
        __syncthreads();
        if (act) {
            float nA = fmaxf(sc[t], sd[t] + lA);   // max-plus compose right∘left
            float nB = fmaxf(sd[t] + lB, NEGINF);
            sc[t] = nA; sd[t] = nB;
        }
        __syncthreads();
    }
    float inc_c = (c == 0) ? NEGINF : sc[c - 1];
    __syncthreads();

    float u = u_pred[i];
    bool gate = u >= THRES_UP;
    float uh = gate ? (openA[i] ? fmaxf(m_loc[i], inc_c) : m_loc[i]) : u;
    out[3 * SEQ + i] = uh;   // up_hats
    out[2 * SEQ + i] = u;    // u_pred passthrough
    sc[t] = uh;
    sd[t] = (1.0f - uh) * a[i];
    __syncthreads();
    for (int d = 1; d < 256; d <<= 1) {
        float lc = 1.0f, ld = 0.0f;
        bool act = t >= d;
        if (act) { lc = sc[t - d]; ld = sd[t - d]; }
        __syncthreads();
        if (act) { sd[t] = sc[t] * ld + sd[t]; sc[t] = sc[t] * lc; }
        __syncthreads();
    }
    Pc[i] = sc[t];
    Qc[i] = sd[t];
    if (t == 255) { Pch[c] = sc[255]; Qch[c] = sd[255]; }
}

// ---- L3: redundant affine scan of Pch/Qch -> alphaIn_c; finalize alpha;
//          per-chunk affine scan of y pairs (into Pc/Qc as Ec/Fc) ----
__global__ __launch_bounds__(256) void k_alpha_y(
        float* __restrict__ Pc, float* __restrict__ Qc,
        const float* __restrict__ Pch, const float* __restrict__ Qch,
        float* __restrict__ out,
        float* __restrict__ Ech, float* __restrict__ Fch) {
    __shared__ float sc[256], sd[256];
    int t = threadIdx.x, c = blockIdx.x;
    int i = c * CHUNK + t;

    sc[t] = Pch[t]; sd[t] = Qch[t];
    __syncthreads();
    for (int d = 1; d < 256; d <<= 1) {
        float lc = 1.0f, ld = 0.0f;
        bool act = t >= d;
        if (act) { lc = sc[t - d]; ld = sd[t - d]; }
        __syncthreads();
        if (act) { sd[t] = sc[t] * ld + sd[t]; sc[t] = sc[t] * lc; }
        __syncthreads();
    }
    float alphaIn_c = (c == 0) ? 0.0f : sd[c - 1];
    __syncthreads();

    float al = Pc[i] * alphaIn_c + Qc[i];
    out[SEQ + i] = al;  // alphas
    float uh = out[3 * SEQ + i];
    bool gate = uh >= THRES_UP;
    sc[t] = gate ? (1.0f - al) : 0.0f;
    sd[t] = gate ? al * uh : 0.0f;
    __syncthreads();
    for (int d = 1; d < 256; d <<= 1) {
        float lc = 1.0f, ld = 0.0f;
        bool act = t >= d;
        if (act) { lc = sc[t - d]; ld = sd[t - d]; }
        __syncthreads();
        if (act) { sd[t] = sc[t] * ld + sd[t]; sc[t] = sc[t] * lc; }
        __syncthreads();
    }
    Pc[i] = sc[t];  // Ec
    Qc[i] = sd[t];  // Fc
    if (t == 255) { Ech[c] = sc[255]; Fch[c] = sd[255]; }
}

// ---- L4: redundant affine scan of Ech/Fch (full y-prefix in LDS) + redundant
//          max scans of trigLast/fallLast; finalize y; loss/cnt ----
__global__ __launch_bounds__(256) void k_yfinal_loss(
        const float* __restrict__ Ec, const float* __restrict__ Fc,
        const float* __restrict__ Ech, const float* __restrict__ Fch,
        const int* __restrict__ trigLast, const int* __restrict__ fallLast,
        const float* __restrict__ u_pred, const float* __restrict__ label,
        const float* __restrict__ thres2,
        const int* __restrict__ ltLoc, const int* __restrict__ lfExcl,
        float* __restrict__ out) {
    __shared__ float sc[256], sd[256], syIn[256];
    __shared__ int   st[256], sf[256];
    int t = threadIdx.x, c = blockIdx.x;
    int i = c * CHUNK + t;

    sc[t] = Ech[t]; sd[t] = Fch[t];
    st[t] = trigLast[t]; sf[t] = fallLast[t];
    __syncthreads();
    for (int d = 1; d < 256; d <<= 1) {
        float lc = 1.0f, ld = 0.0f; int lt = -1, lf = -1;
        bool act = t >= d;
        if (act) { lc = sc[t - d]; ld = sd[t - d]; lt = st[t - d]; lf = sf[t - d]; }
        __syncthreads();
        if (act) {
            sd[t] = sc[t] * ld + sd[t]; sc[t] = sc[t] * lc;
            st[t] = max(st[t], lt);
            sf[t] = max(sf[t], lf);
        }
        __syncthreads();
    }
    syIn[t] = (t == 0) ? 0.0f : sd[t - 1];   // incoming y for chunk t
    int trigIn_c = (c == 0) ? -1 : st[c - 1];
    int fallIn_c = (c == 0) ? -1 : sf[c - 1];
    __syncthreads();

    out[i] = Ec[i] * syIn[c] + Fc[i];  // ys

    float u = u_pred[i];
    bool gate = u >= THRES_UP;
    bool gprev = (i > 0) && (u_pred[i - 1] >= THRES_UP);
    bool fall = gprev && !gate;
    float contrib = 0.0f;
    int flag = 0;
    if (fall) {
        int j  = max(ltLoc[i], trigIn_c);    // last label-trigger <= i
        int pf = max(lfExcl[i], fallIn_c);   // last fall < i
        float lc = 0.0f;
        if (j > pf) {
            bool gj = u_pred[j] >= THRES_UP;
            float yj = Ec[j] * syIn[j >> 8] + Fc[j];
            float d = yj - label[j];
            lc = gj ? d * d : -1.0f;
        }
        bool isneg = (lc == -1.0f);
        bool nonzero = (lc != 0.0f);
        if (!isneg) {
            if (nonzero) { contrib = lc; flag = 1; }   // * R, R = 1.0
            else {
                int ip = i - 1;
                float ypre = Ec[ip] * syIn[ip >> 8] + Fc[ip];
                if (ypre >= THRES1) {
                    float t2 = thres2[(i < 59) ? i : 59];
                    float d2 = ypre - t2;
                    contrib = d2 * d2; flag = 1;
                }
            }
        }
    }
    #pragma unroll
    for (int off = 32; off; off >>= 1) {
        contrib += __shfl_down(contrib, off, 64);
        flag    += __shfl_down(flag, off, 64);
    }
    if ((t & 63) == 0 && (contrib != 0.0f || flag != 0)) {
        atomicAdd(&out[4 * SEQ], contrib);
        atomicAdd(&out[4 * SEQ + 1], (float)flag);
    }
}

extern "C" void kernel_launch(void* const* d_in, const int* in_sizes, int n_in,
                              void* d_out, int out_size, void* d_ws, size_t ws_size,
                              hipStream_t stream) {
    const float* h      = (const float*)d_in[0];
    const float* W      = (const float*)d_in[1];
    const float* b      = (const float*)d_in[2];
    const float* u_pred = (const float*)d_in[4];
    const float* label  = (const float*)d_in[5];
    const float* thres2 = (const float*)d_in[6];
    float* out  = (float*)d_out;
    float* base = (float*)d_ws;

    float* a      = base;
    float* m_loc  = base + SEQ;
    float* Pc     = base + 2 * (size_t)SEQ;
    float* Qc     = base + 3 * (size_t)SEQ;
    int*   openA  = (int*)(base + 4 * (size_t)SEQ);
    int*   ltLoc  = (int*)(base + 5 * (size_t)SEQ);
    int*   lfExcl = (int*)(base + 6 * (size_t)SEQ);
    float* sums   = base + 7 * (size_t)SEQ;
    float* lastm   = sums;
    float* Pch     = sums + NCH;
    float* Qch     = sums + 2 * NCH;
    float* Ech     = sums + 3 * NCH;
    float* Fch     = sums + 4 * NCH;
    int*   lastopen = (int*)(sums + 5 * NCH);
    int*   lastgate = (int*)(sums + 6 * NCH);
    int*   trigLast = (int*)(sums + 7 * NCH);
    int*   fallLast = (int*)(sums + 8 * NCH);

    k_matvec_local<<<SEQ / 4, 256, 0, stream>>>(h, W, b, u_pred, label, a,
                                                m_loc, openA, ltLoc, lfExcl,
                                                lastm, lastopen, lastgate, trigLast, fallLast,
                                                out + 4 * SEQ);
    k_uphat_alpha<<<NCH, CHUNK, 0, stream>>>(u_pred, a, m_loc, openA,
                                             lastm, lastopen, lastgate,
                                             Pc, Qc, Pch, Qch, out);
    k_alpha_y<<<NCH, CHUNK, 0, stream>>>(Pc, Qc, Pch, Qch, out, Ech, Fch);
    k_yfinal_loss<<<NCH, CHUNK, 0, stream>>>(Pc, Qc, Ech, Fch, trigLast, fallLast,
                                             u_pred, label, thres2, ltLoc, lfExcl, out);
}